// Round 1
// baseline (952.750 us; speedup 1.0000x reference)
//
#include <hip/hip_runtime.h>
#include <hip/hip_bf16.h>

typedef __attribute__((ext_vector_type(8))) short bf16x8;
typedef __attribute__((ext_vector_type(4))) float f32x4;

#define MFMA(a,b,c) __builtin_amdgcn_mfma_f32_16x16x32_bf16((a),(b),(c),0,0,0)

static constexpr int NTOK = 8 * 8 * 56 * 56;   // 200704 tokens
static constexpr int NT   = 98;                // tokens per window
static constexpr int NWIN = 2048;              // total windows

__device__ __forceinline__ unsigned short f2bf(float f) {
  union { float f; unsigned u; } v; v.f = f;
  unsigned r = v.u + 0x7FFFu + ((v.u >> 16) & 1u);
  return (unsigned short)(r >> 16);
}

// ---------------- K0: weight transpose + bf16 cast -------------------------
// qkvT [384][128], projT [128][128], fc1T [512][128], fc2T [128][512]
__global__ __launch_bounds__(256) void k0_prep(
    const float* __restrict__ qkv_w, const float* __restrict__ proj_w,
    const float* __restrict__ fc1_w, const float* __restrict__ fc2_w,
    unsigned short* __restrict__ qkvT, unsigned short* __restrict__ projT,
    unsigned short* __restrict__ fc1T, unsigned short* __restrict__ fc2T) {
  int idx = blockIdx.x * 256 + threadIdx.x;
  if (idx < 384 * 128) { int n = idx >> 7, k = idx & 127; qkvT[idx] = f2bf(qkv_w[k * 384 + n]); }
  if (idx < 128 * 128) { int n = idx >> 7, k = idx & 127; projT[idx] = f2bf(proj_w[k * 128 + n]); }
  if (idx < 512 * 128) { int n = idx >> 7, k = idx & 127; fc1T[idx] = f2bf(fc1_w[k * 512 + n]); }
  if (idx < 128 * 512) { int n = idx >> 9, k = idx & 511; fc2T[idx] = f2bf(fc2_w[k * 128 + n]); }
}

// ---------------- K1: LN1 + cyclic shift + window partition ----------------
// one wave per window-token; output win[t][128] bf16, t = widx*98 + n
__global__ __launch_bounds__(256) void k1_ln_part(
    const float* __restrict__ x, const float* __restrict__ g,
    const float* __restrict__ b, unsigned short* __restrict__ win) {
  int wv = threadIdx.x >> 6, lane = threadIdx.x & 63;
  int t = blockIdx.x * 4 + wv;
  int widx = t / NT, n = t - widx * NT;
  int bb = widx >> 8, wb = widx & 255;
  int dW = wb >> 6, hW = (wb >> 3) & 7, wW = wb & 7;
  int dr = n / 49, rem = n - dr * 49, hr = rem / 7, wr = rem - hr * 7;
  int ds = (dW * 2 + dr + 1) & 7;              // roll -SD then partition (SD=1)
  int hs = hW * 7 + hr + 3; if (hs >= 56) hs -= 56;
  int wsv = wW * 7 + wr + 3; if (wsv >= 56) wsv -= 56;
  size_t srow = ((size_t)(bb * 8 + ds) * 56 + hs) * 56 + wsv;
  const float2 v2 = *(const float2*)(x + srow * 128 + lane * 2);
  float s = v2.x + v2.y, ss = v2.x * v2.x + v2.y * v2.y;
#pragma unroll
  for (int m = 1; m < 64; m <<= 1) { s += __shfl_xor(s, m); ss += __shfl_xor(ss, m); }
  float mu = s * (1.f / 128.f);
  float var = ss * (1.f / 128.f) - mu * mu;
  float inv = rsqrtf(var + 1e-5f);
  float g0 = g[lane * 2], g1 = g[lane * 2 + 1];
  float b0 = b[lane * 2], b1 = b[lane * 2 + 1];
  unsigned short o0 = f2bf((v2.x - mu) * inv * g0 + b0);
  unsigned short o1 = f2bf((v2.y - mu) * inv * g1 + b1);
  *(unsigned*)(win + (size_t)t * 128 + lane * 2) = (unsigned)o0 | ((unsigned)o1 << 16);
}

// ---------------- K2: QKV GEMM [200704,128]@[128,384] ----------------------
// block = 16-row M-tile; wave w covers cols [w*96, w*96+96)
__global__ __launch_bounds__(256) void k2_qkv(
    const unsigned short* __restrict__ win, const unsigned short* __restrict__ qkvT,
    const float* __restrict__ qkv_b,
    unsigned short* __restrict__ q, unsigned short* __restrict__ k,
    unsigned short* __restrict__ v) {
  int wv = threadIdx.x >> 6, lane = threadIdx.x & 63;
  int l15 = lane & 15, lhi = lane >> 4;
  int mbase = blockIdx.x * 16;
  const unsigned short* arow = win + (size_t)(mbase + l15) * 128 + lhi * 8;
  bf16x8 afr[4];
#pragma unroll
  for (int ks = 0; ks < 4; ++ks) afr[ks] = *(const bf16x8*)(arow + ks * 32);
  int nt0 = wv * 6;
  f32x4 acc[6] = {};
#pragma unroll
  for (int ks = 0; ks < 4; ++ks)
#pragma unroll
    for (int nt = 0; nt < 6; ++nt) {
      int col = (nt0 + nt) * 16 + l15;
      bf16x8 bfr = *(const bf16x8*)(qkvT + (size_t)col * 128 + ks * 32 + lhi * 8);
      acc[nt] = MFMA(afr[ks], bfr, acc[nt]);
    }
#pragma unroll
  for (int nt = 0; nt < 6; ++nt) {
    int col = (nt0 + nt) * 16 + l15;
    int which = col >> 7, head = (col >> 5) & 3, hd = col & 31;
    unsigned short* outb = which == 0 ? q : (which == 1 ? k : v);
    float scale = which == 0 ? 0.17677669529663687f : 1.0f;
    float bias = qkv_b[col];
#pragma unroll
    for (int j = 0; j < 4; ++j) {
      int row = mbase + lhi * 4 + j;
      int widx = row / NT, n = row - widx * NT;
      float val = (acc[nt][j] + bias) * scale;
      outb[(size_t)((widx * 4 + head) * NT + n) * 32 + hd] = f2bf(val);
    }
  }
}

// ---------------- K3: window attention, one block per (window, head) -------
__global__ __launch_bounds__(256) void k3_attn(
    const unsigned short* __restrict__ q, const unsigned short* __restrict__ kk,
    const unsigned short* __restrict__ vv, const float* __restrict__ mask,
    const int* __restrict__ rel, const float* __restrict__ rpb,
    unsigned short* __restrict__ out) {
  __shared__ __align__(16) unsigned short Pl[112 * 136];
  __shared__ __align__(16) unsigned short Vt[32 * 136];
  int bid = blockIdx.x;
  int widx = bid >> 2, head = bid & 3;
  int wb = widx & 255;
  size_t base = (size_t)(widx * 4 + head) * NT * 32;
  int tid = threadIdx.x, wv = tid >> 6, lane = tid & 63;
  int l15 = lane & 15, lhi = lane >> 4;

  // stage V transposed: Vt[d][key], keys >= 98 zeroed (avoid NaN garbage)
  for (int idx = tid; idx < NT * 32; idx += 256) {
    int j = idx >> 5, d = idx & 31;
    Vt[d * 136 + j] = vv[base + idx];
  }
  for (int idx = tid; idx < 32 * 30; idx += 256) {
    int d = idx / 30, j = 98 + idx % 30;
    Vt[d * 136 + j] = 0;
  }

  // S = Q@K^T (K-dim = 32, single MFMA step), softmax, P -> LDS
  for (int mt = wv; mt < 7; mt += 4) {
    int mb = mt * 16;
    bf16x8 afr = *(const bf16x8*)(q + base + (size_t)(mb + l15) * 32 + lhi * 8);
    f32x4 sfr[7];
#pragma unroll
    for (int nt = 0; nt < 7; ++nt) {
      bf16x8 bfr = *(const bf16x8*)(kk + base + (size_t)(nt * 16 + l15) * 32 + lhi * 8);
      f32x4 zz = {};
      sfr[nt] = MFMA(afr, bfr, zz);
    }
#pragma unroll
    for (int j = 0; j < 4; ++j) {
      int i = mb + lhi * 4 + j;
      bool irow = i < NT;
      float sv[7];
#pragma unroll
      for (int nt = 0; nt < 7; ++nt) {
        int colc = nt * 16 + l15;
        float s = fminf(fmaxf(sfr[nt][j], -1e4f), 1e4f);  // neutralize pad garbage/NaN
        float bm;
        if (irow && colc < NT)
          bm = rpb[rel[i * NT + colc] * 4 + head] + mask[(size_t)wb * NT * NT + i * NT + colc];
        else
          bm = -1e30f;
        sv[nt] = s + bm;
      }
      float mx = sv[0];
#pragma unroll
      for (int nt = 1; nt < 7; ++nt) mx = fmaxf(mx, sv[nt]);
#pragma unroll
      for (int m2 = 1; m2 < 16; m2 <<= 1) mx = fmaxf(mx, __shfl_xor(mx, m2));
      float sum = 0.f, p[7];
#pragma unroll
      for (int nt = 0; nt < 7; ++nt) { p[nt] = __expf(sv[nt] - mx); sum += p[nt]; }
#pragma unroll
      for (int m2 = 1; m2 < 16; m2 <<= 1) sum += __shfl_xor(sum, m2);
      float inv = 1.0f / sum;
#pragma unroll
      for (int nt = 0; nt < 7; ++nt)
        Pl[i * 136 + nt * 16 + l15] = f2bf(p[nt] * inv);
      Pl[i * 136 + 112 + l15] = 0;   // zero pad cols 112..127
    }
  }
  __syncthreads();

  // O = P @ V   (K = 128 padded), store to out[token][head*32 + d]
  for (int mt = wv; mt < 7; mt += 4) {
    int mb = mt * 16;
    f32x4 ofr[2] = {};
#pragma unroll
    for (int ks = 0; ks < 4; ++ks) {
      bf16x8 afr = *(const bf16x8*)(Pl + (mb + l15) * 136 + ks * 32 + lhi * 8);
#pragma unroll
      for (int nt = 0; nt < 2; ++nt) {
        bf16x8 bfr = *(const bf16x8*)(Vt + (nt * 16 + l15) * 136 + ks * 32 + lhi * 8);
        ofr[nt] = MFMA(afr, bfr, ofr[nt]);
      }
    }
#pragma unroll
    for (int nt = 0; nt < 2; ++nt)
#pragma unroll
      for (int j = 0; j < 4; ++j) {
        int n = mb + lhi * 4 + j;
        if (n < NT) {
          int d = nt * 16 + l15;
          out[(size_t)(widx * NT + n) * 128 + head * 32 + d] = f2bf(ofr[nt][j]);
        }
      }
  }
}

// ---------------- K4: proj + reverse/unshift + residual + LN2 --------------
__global__ __launch_bounds__(256) void k4_proj_ln(
    const unsigned short* __restrict__ ao, const unsigned short* __restrict__ projT,
    const float* __restrict__ proj_b, const float* __restrict__ x,
    const float* __restrict__ g2, const float* __restrict__ b2,
    unsigned short* __restrict__ z) {
  int wv = threadIdx.x >> 6, lane = threadIdx.x & 63;
  int l15 = lane & 15, lhi = lane >> 4;
  int mbase = blockIdx.x * 64 + wv * 16;
  const unsigned short* arow = ao + (size_t)(mbase + l15) * 128 + lhi * 8;
  bf16x8 afr[4];
#pragma unroll
  for (int ks = 0; ks < 4; ++ks) afr[ks] = *(const bf16x8*)(arow + ks * 32);
  f32x4 acc[8] = {};
#pragma unroll
  for (int ks = 0; ks < 4; ++ks)
#pragma unroll
    for (int nt = 0; nt < 8; ++nt) {
      bf16x8 bfr = *(const bf16x8*)(projT + (size_t)(nt * 16 + l15) * 128 + ks * 32 + lhi * 8);
      acc[nt] = MFMA(afr[ks], bfr, acc[nt]);
    }
#pragma unroll
  for (int j = 0; j < 4; ++j) {
    int t = mbase + lhi * 4 + j;
    int widx = t / NT, n = t - widx * NT;
    int bb = widx >> 8, wb = widx & 255;
    int dW = wb >> 6, hW = (wb >> 3) & 7, wW = wb & 7;
    int dr = n / 49, rem = n - dr * 49, hr = rem / 7, wr = rem - hr * 7;
    int d = (dW * 2 + dr + 1) & 7;
    int h = hW * 7 + hr + 3; if (h >= 56) h -= 56;
    int w = wW * 7 + wr + 3; if (w >= 56) w -= 56;
    size_t srow = ((size_t)(bb * 8 + d) * 56 + h) * 56 + w;
    float vals[8], s = 0.f, ss = 0.f;
#pragma unroll
    for (int nt = 0; nt < 8; ++nt) {
      int colc = nt * 16 + l15;
      float val = acc[nt][j] + proj_b[colc] + x[srow * 128 + colc];
      vals[nt] = val; s += val; ss += val * val;
    }
#pragma unroll
    for (int m2 = 1; m2 < 16; m2 <<= 1) { s += __shfl_xor(s, m2); ss += __shfl_xor(ss, m2); }
    float mu = s * (1.f / 128.f);
    float var = ss * (1.f / 128.f) - mu * mu;
    float inv = rsqrtf(var + 1e-5f);
#pragma unroll
    for (int nt = 0; nt < 8; ++nt) {
      int colc = nt * 16 + l15;
      z[srow * 128 + colc] = f2bf((vals[nt] - mu) * inv * g2[colc] + b2[colc]);
    }
  }
}

// ---------------- K5: MLP fc1 + GELU + fc2 ---------------------------------
// wave = 32 rows; hidden chunked by 64 (VGPR control); h through per-wave LDS
__global__ __launch_bounds__(256) void k5_mlp(
    const unsigned short* __restrict__ z, const unsigned short* __restrict__ fc1T,
    const float* __restrict__ fc1_b, const unsigned short* __restrict__ fc2T,
    const float* __restrict__ fc2_b, float* __restrict__ out) {
  __shared__ __align__(16) unsigned short hl[4][32 * 72];
  int wv = threadIdx.x >> 6, lane = threadIdx.x & 63;
  int l15 = lane & 15, lhi = lane >> 4;
  int mbase = blockIdx.x * 128 + wv * 32;
  unsigned short* hw = hl[wv];
  bf16x8 afr[2][4];
#pragma unroll
  for (int mt = 0; mt < 2; ++mt)
#pragma unroll
    for (int ks = 0; ks < 4; ++ks)
      afr[mt][ks] = *(const bf16x8*)(z + (size_t)(mbase + mt * 16 + l15) * 128 + ks * 32 + lhi * 8);
  f32x4 oacc[2][8] = {};
  for (int ch = 0; ch < 8; ++ch) {
    f32x4 hacc[2][4] = {};
#pragma unroll
    for (int ks = 0; ks < 4; ++ks)
#pragma unroll
      for (int nt = 0; nt < 4; ++nt) {
        int hcol = ch * 64 + nt * 16 + l15;
        bf16x8 bfr = *(const bf16x8*)(fc1T + (size_t)hcol * 128 + ks * 32 + lhi * 8);
#pragma unroll
        for (int mt = 0; mt < 2; ++mt)
          hacc[mt][nt] = MFMA(afr[mt][ks], bfr, hacc[mt][nt]);
      }
#pragma unroll
    for (int mt = 0; mt < 2; ++mt)
#pragma unroll
      for (int nt = 0; nt < 4; ++nt)
#pragma unroll
        for (int j = 0; j < 4; ++j) {
          int r = mt * 16 + lhi * 4 + j;
          int hcol = ch * 64 + nt * 16 + l15;
          float hv = hacc[mt][nt][j] + fc1_b[hcol];
          float gv = 0.5f * hv * (1.0f + erff(hv * 0.70710678118654752f));
          hw[r * 72 + nt * 16 + l15] = f2bf(gv);
        }
    __syncthreads();
#pragma unroll
    for (int ks = 0; ks < 2; ++ks) {
      bf16x8 a2[2];
#pragma unroll
      for (int mt = 0; mt < 2; ++mt)
        a2[mt] = *(const bf16x8*)(hw + (mt * 16 + l15) * 72 + ks * 32 + lhi * 8);
#pragma unroll
      for (int nt = 0; nt < 8; ++nt) {
        int ocol = nt * 16 + l15;
        bf16x8 bfr = *(const bf16x8*)(fc2T + (size_t)ocol * 512 + ch * 64 + ks * 32 + lhi * 8);
#pragma unroll
        for (int mt = 0; mt < 2; ++mt)
          oacc[mt][nt] = MFMA(a2[mt], bfr, oacc[mt][nt]);
      }
    }
    __syncthreads();
  }
#pragma unroll
  for (int mt = 0; mt < 2; ++mt)
#pragma unroll
    for (int nt = 0; nt < 8; ++nt)
#pragma unroll
      for (int j = 0; j < 4; ++j) {
        int r = mbase + mt * 16 + lhi * 4 + j;
        out[(size_t)r * 128 + nt * 16 + l15] = oacc[mt][nt][j] + fc2_b[nt * 16 + l15];
      }
}

// ---------------------------------------------------------------------------
extern "C" void kernel_launch(void* const* d_in, const int* in_sizes, int n_in,
                              void* d_out, int out_size, void* d_ws, size_t ws_size,
                              hipStream_t stream) {
  const float* x      = (const float*)d_in[0];
  const float* mask   = (const float*)d_in[1];
  const int*   rel    = (const int*)d_in[2];
  const float* n1g    = (const float*)d_in[3];
  const float* n1b    = (const float*)d_in[4];
  const float* qkv_w  = (const float*)d_in[5];
  const float* qkv_b  = (const float*)d_in[6];
  const float* rpb    = (const float*)d_in[7];
  const float* proj_w = (const float*)d_in[8];
  const float* proj_b = (const float*)d_in[9];
  const float* n2g    = (const float*)d_in[10];
  const float* n2b    = (const float*)d_in[11];
  const float* fc1_w  = (const float*)d_in[12];
  const float* fc1_b  = (const float*)d_in[13];
  const float* fc2_w  = (const float*)d_in[14];
  const float* fc2_b  = (const float*)d_in[15];
  float* out = (float*)d_out;

  char* ws = (char*)d_ws;
  const size_t SZ = (size_t)NTOK * 128 * 2;            // 51,380,224 B
  unsigned short* win  = (unsigned short*)(ws);
  unsigned short* qb   = (unsigned short*)(ws + SZ);
  unsigned short* kb   = (unsigned short*)(ws + 2 * SZ);
  unsigned short* vb   = (unsigned short*)(ws + 3 * SZ);
  unsigned short* qkvT = (unsigned short*)(ws + 4 * SZ);
  unsigned short* projT = qkvT + 384 * 128;
  unsigned short* fc1T  = projT + 128 * 128;
  unsigned short* fc2T  = fc1T + 512 * 128;
  unsigned short* ao = win;   // attn output reuses win buffer (win dead after k2)
  unsigned short* zb = qb;    // LN2 output reuses q buffer (q dead after k3)

  k0_prep<<<256, 256, 0, stream>>>(qkv_w, proj_w, fc1_w, fc2_w, qkvT, projT, fc1T, fc2T);
  k1_ln_part<<<NTOK / 4, 256, 0, stream>>>(x, n1g, n1b, win);
  k2_qkv<<<NTOK / 16, 256, 0, stream>>>(win, qkvT, qkv_b, qb, kb, vb);
  k3_attn<<<NWIN * 4, 256, 0, stream>>>(qb, kb, vb, mask, rel, rpb, ao);
  k4_proj_ln<<<NTOK / 64, 256, 0, stream>>>(ao, projT, proj_b, x, n2g, n2b, zb);
  k5_mlp<<<NTOK / 128, 256, 0, stream>>>(zb, fc1T, fc1_b, fc2T, fc2_b, out);
}

// Round 2
// 734.544 us; speedup vs baseline: 1.2971x; 1.2971x over previous
//
#include <hip/hip_runtime.h>
#include <hip/hip_bf16.h>

typedef __attribute__((ext_vector_type(8))) short bf16x8;
typedef __attribute__((ext_vector_type(4))) float f32x4;

#define MFMA(a,b,c) __builtin_amdgcn_mfma_f32_16x16x32_bf16((a),(b),(c),0,0,0)
#define WAVE_LDS_FENCE() do { asm volatile("s_waitcnt lgkmcnt(0)" ::: "memory"); \
                              __builtin_amdgcn_sched_barrier(0); } while (0)

static constexpr int NTOK = 8 * 8 * 56 * 56;   // 200704 tokens
static constexpr int NT   = 98;                // tokens per window
static constexpr int NWIN = 2048;              // total windows

__device__ __forceinline__ unsigned short f2bf(float f) {
  union { float f; unsigned u; } v; v.f = f;
  unsigned r = v.u + 0x7FFFu + ((v.u >> 16) & 1u);
  return (unsigned short)(r >> 16);
}

// ---------------- K0: weight transpose + bf16 cast + bias table ------------
// qkvT [384][128], projT [128][128], fc1T [512][128], fc2T [128][512]
// biasH [4][98][98] fp32 = rpb[rel[i][j]][head]
__global__ __launch_bounds__(256) void k0_prep(
    const float* __restrict__ qkv_w, const float* __restrict__ proj_w,
    const float* __restrict__ fc1_w, const float* __restrict__ fc2_w,
    const int* __restrict__ rel, const float* __restrict__ rpb,
    unsigned short* __restrict__ qkvT, unsigned short* __restrict__ projT,
    unsigned short* __restrict__ fc1T, unsigned short* __restrict__ fc2T,
    float* __restrict__ biasH) {
  int idx = blockIdx.x * 256 + threadIdx.x;
  if (idx < 384 * 128) { int n = idx >> 7, k = idx & 127; qkvT[idx] = f2bf(qkv_w[k * 384 + n]); }
  if (idx < 128 * 128) { int n = idx >> 7, k = idx & 127; projT[idx] = f2bf(proj_w[k * 128 + n]); }
  if (idx < 512 * 128) { int n = idx >> 7, k = idx & 127; fc1T[idx] = f2bf(fc1_w[k * 512 + n]); }
  if (idx < 128 * 512) { int n = idx >> 9, k = idx & 511; fc2T[idx] = f2bf(fc2_w[k * 128 + n]); }
  if (idx < 4 * NT * NT) {
    int h = idx / (NT * NT), r = idx % (NT * NT);
    biasH[idx] = rpb[rel[r] * 4 + h];
  }
}

// ---------------- K1: LN1 + cyclic shift + window partition ----------------
__global__ __launch_bounds__(256) void k1_ln_part(
    const float* __restrict__ x, const float* __restrict__ g,
    const float* __restrict__ b, unsigned short* __restrict__ win) {
  int wv = threadIdx.x >> 6, lane = threadIdx.x & 63;
  int t = blockIdx.x * 4 + wv;
  int widx = t / NT, n = t - widx * NT;
  int bb = widx >> 8, wb = widx & 255;
  int dW = wb >> 6, hW = (wb >> 3) & 7, wW = wb & 7;
  int dr = n / 49, rem = n - dr * 49, hr = rem / 7, wr = rem - hr * 7;
  int ds = (dW * 2 + dr + 1) & 7;
  int hs = hW * 7 + hr + 3; if (hs >= 56) hs -= 56;
  int wsv = wW * 7 + wr + 3; if (wsv >= 56) wsv -= 56;
  size_t srow = ((size_t)(bb * 8 + ds) * 56 + hs) * 56 + wsv;
  const float2 v2 = *(const float2*)(x + srow * 128 + lane * 2);
  float s = v2.x + v2.y, ss = v2.x * v2.x + v2.y * v2.y;
#pragma unroll
  for (int m = 1; m < 64; m <<= 1) { s += __shfl_xor(s, m); ss += __shfl_xor(ss, m); }
  float mu = s * (1.f / 128.f);
  float var = ss * (1.f / 128.f) - mu * mu;
  float inv = rsqrtf(var + 1e-5f);
  float g0 = g[lane * 2], g1 = g[lane * 2 + 1];
  float b0 = b[lane * 2], b1 = b[lane * 2 + 1];
  unsigned short o0 = f2bf((v2.x - mu) * inv * g0 + b0);
  unsigned short o1 = f2bf((v2.y - mu) * inv * g1 + b1);
  *(unsigned*)(win + (size_t)t * 128 + lane * 2) = (unsigned)o0 | ((unsigned)o1 << 16);
}

// ---------------- K2: QKV GEMM [200704,128]@[128,384] ----------------------
__global__ __launch_bounds__(256) void k2_qkv(
    const unsigned short* __restrict__ win, const unsigned short* __restrict__ qkvT,
    const float* __restrict__ qkv_b,
    unsigned short* __restrict__ q, unsigned short* __restrict__ k,
    unsigned short* __restrict__ v) {
  int wv = threadIdx.x >> 6, lane = threadIdx.x & 63;
  int l15 = lane & 15, lhi = lane >> 4;
  int mbase = blockIdx.x * 16;
  const unsigned short* arow = win + (size_t)(mbase + l15) * 128 + lhi * 8;
  bf16x8 afr[4];
#pragma unroll
  for (int ks = 0; ks < 4; ++ks) afr[ks] = *(const bf16x8*)(arow + ks * 32);
  int nt0 = wv * 6;
  f32x4 acc[6] = {};
#pragma unroll
  for (int ks = 0; ks < 4; ++ks)
#pragma unroll
    for (int nt = 0; nt < 6; ++nt) {
      int col = (nt0 + nt) * 16 + l15;
      bf16x8 bfr = *(const bf16x8*)(qkvT + (size_t)col * 128 + ks * 32 + lhi * 8);
      acc[nt] = MFMA(afr[ks], bfr, acc[nt]);
    }
#pragma unroll
  for (int nt = 0; nt < 6; ++nt) {
    int col = (nt0 + nt) * 16 + l15;
    int which = col >> 7, head = (col >> 5) & 3, hd = col & 31;
    unsigned short* outb = which == 0 ? q : (which == 1 ? k : v);
    float scale = which == 0 ? 0.17677669529663687f : 1.0f;
    float bias = qkv_b[col];
#pragma unroll
    for (int j = 0; j < 4; ++j) {
      int row = mbase + lhi * 4 + j;
      int widx = row / NT, n = row - widx * NT;
      float val = (acc[nt][j] + bias) * scale;
      outb[(size_t)((widx * 4 + head) * NT + n) * 32 + hd] = f2bf(val);
    }
  }
}

// ---------------- K3: window attention, one block per (window, head) -------
// per-wave P tile (no inter-wave barrier after V staging); bias table gather-free
__global__ __launch_bounds__(256) void k3_attn(
    const unsigned short* __restrict__ q, const unsigned short* __restrict__ kk,
    const unsigned short* __restrict__ vv, const float* __restrict__ mask,
    const float* __restrict__ biasH, unsigned short* __restrict__ out) {
  __shared__ __align__(16) unsigned short Vt[32 * 140];
  __shared__ __align__(16) unsigned short Pw[4][16 * 140];
  int bid = blockIdx.x;
  int widx = bid >> 2, head = bid & 3;
  int wb = widx & 255;
  size_t base = (size_t)(widx * 4 + head) * NT * 32;
  int tid = threadIdx.x, wv = tid >> 6, lane = tid & 63;
  int l15 = lane & 15, lhi = lane >> 4;

  // stage V transposed: Vt[d][key], keys >= 98 zeroed
  for (int idx = tid; idx < NT * 32; idx += 256) {
    int j = idx >> 5, d = idx & 31;
    Vt[d * 140 + j] = vv[base + idx];
  }
  for (int idx = tid; idx < 32 * 30; idx += 256) {
    int d = idx / 30, j = 98 + idx % 30;
    Vt[d * 140 + j] = 0;
  }
  __syncthreads();

  const float* maskw = mask + (size_t)wb * NT * NT;
  const float* biash = biasH + head * NT * NT;
  unsigned short* P = Pw[wv];

  for (int mt = wv; mt < 7; mt += 4) {
    int mb = mt * 16;
    bf16x8 afr = *(const bf16x8*)(q + base + (size_t)(mb + l15) * 32 + lhi * 8);
    f32x4 sfr[7];
#pragma unroll
    for (int nt = 0; nt < 7; ++nt) {
      bf16x8 bfr = *(const bf16x8*)(kk + base + (size_t)(nt * 16 + l15) * 32 + lhi * 8);
      f32x4 zz = {};
      sfr[nt] = MFMA(afr, bfr, zz);
    }
#pragma unroll
    for (int j = 0; j < 4; ++j) {
      int i = mb + lhi * 4 + j;
      int ic = i < 97 ? i : 97;
      float sv[7];
#pragma unroll
      for (int nt = 0; nt < 7; ++nt) {
        int colc = nt * 16 + l15;
        int jc = colc < 97 ? colc : 97;
        float s = fminf(fmaxf(sfr[nt][j], -1e4f), 1e4f);
        float bm = biash[ic * NT + jc] + maskw[ic * NT + jc];
        sv[nt] = (i < NT && colc < NT) ? (s + bm) : -1e30f;
      }
      float mx = sv[0];
#pragma unroll
      for (int nt = 1; nt < 7; ++nt) mx = fmaxf(mx, sv[nt]);
#pragma unroll
      for (int m2 = 1; m2 < 16; m2 <<= 1) mx = fmaxf(mx, __shfl_xor(mx, m2));
      float sum = 0.f, p[7];
#pragma unroll
      for (int nt = 0; nt < 7; ++nt) { p[nt] = __expf(sv[nt] - mx); sum += p[nt]; }
#pragma unroll
      for (int m2 = 1; m2 < 16; m2 <<= 1) sum += __shfl_xor(sum, m2);
      float inv = 1.0f / sum;
      int iloc = lhi * 4 + j;
#pragma unroll
      for (int nt = 0; nt < 7; ++nt)
        P[iloc * 140 + nt * 16 + l15] = f2bf(p[nt] * inv);
      P[iloc * 140 + 112 + l15] = 0;   // zero pad cols 112..127
    }
    WAVE_LDS_FENCE();   // P writes -> P reads, same wave only

    f32x4 ofr[2] = {};
#pragma unroll
    for (int ks = 0; ks < 4; ++ks) {
      bf16x8 pafr = *(const bf16x8*)(P + l15 * 140 + ks * 32 + lhi * 8);
#pragma unroll
      for (int nt = 0; nt < 2; ++nt) {
        bf16x8 bfr = *(const bf16x8*)(Vt + (nt * 16 + l15) * 140 + ks * 32 + lhi * 8);
        ofr[nt] = MFMA(pafr, bfr, ofr[nt]);
      }
    }
#pragma unroll
    for (int nt = 0; nt < 2; ++nt)
#pragma unroll
      for (int j = 0; j < 4; ++j) {
        int n = mb + lhi * 4 + j;
        if (n < NT) {
          int d = nt * 16 + l15;
          out[(size_t)(widx * NT + n) * 128 + head * 32 + d] = f2bf(ofr[nt][j]);
        }
      }
    WAVE_LDS_FENCE();   // P reads done before next mt overwrites P
  }
}

// ---------------- K4: proj + reverse/unshift + residual + LN2 --------------
__global__ __launch_bounds__(256) void k4_proj_ln(
    const unsigned short* __restrict__ ao, const unsigned short* __restrict__ projT,
    const float* __restrict__ proj_b, const float* __restrict__ x,
    const float* __restrict__ g2, const float* __restrict__ b2,
    unsigned short* __restrict__ z) {
  int wv = threadIdx.x >> 6, lane = threadIdx.x & 63;
  int l15 = lane & 15, lhi = lane >> 4;
  int mbase = blockIdx.x * 64 + wv * 16;
  const unsigned short* arow = ao + (size_t)(mbase + l15) * 128 + lhi * 8;
  bf16x8 afr[4];
#pragma unroll
  for (int ks = 0; ks < 4; ++ks) afr[ks] = *(const bf16x8*)(arow + ks * 32);
  f32x4 acc[8] = {};
#pragma unroll
  for (int ks = 0; ks < 4; ++ks)
#pragma unroll
    for (int nt = 0; nt < 8; ++nt) {
      bf16x8 bfr = *(const bf16x8*)(projT + (size_t)(nt * 16 + l15) * 128 + ks * 32 + lhi * 8);
      acc[nt] = MFMA(afr[ks], bfr, acc[nt]);
    }
#pragma unroll
  for (int j = 0; j < 4; ++j) {
    int t = mbase + lhi * 4 + j;
    int widx = t / NT, n = t - widx * NT;
    int bb = widx >> 8, wb = widx & 255;
    int dW = wb >> 6, hW = (wb >> 3) & 7, wW = wb & 7;
    int dr = n / 49, rem = n - dr * 49, hr = rem / 7, wr = rem - hr * 7;
    int d = (dW * 2 + dr + 1) & 7;
    int h = hW * 7 + hr + 3; if (h >= 56) h -= 56;
    int w = wW * 7 + wr + 3; if (w >= 56) w -= 56;
    size_t srow = ((size_t)(bb * 8 + d) * 56 + h) * 56 + w;
    float vals[8], s = 0.f, ss = 0.f;
#pragma unroll
    for (int nt = 0; nt < 8; ++nt) {
      int colc = nt * 16 + l15;
      float val = acc[nt][j] + proj_b[colc] + x[srow * 128 + colc];
      vals[nt] = val; s += val; ss += val * val;
    }
#pragma unroll
    for (int m2 = 1; m2 < 16; m2 <<= 1) { s += __shfl_xor(s, m2); ss += __shfl_xor(ss, m2); }
    float mu = s * (1.f / 128.f);
    float var = ss * (1.f / 128.f) - mu * mu;
    float inv = rsqrtf(var + 1e-5f);
#pragma unroll
    for (int nt = 0; nt < 8; ++nt) {
      int colc = nt * 16 + l15;
      z[srow * 128 + colc] = f2bf((vals[nt] - mu) * inv * g2[colc] + b2[colc]);
    }
  }
}

// ---------------- K5: MLP fc1 + GELU + fc2 ---------------------------------
// per-wave LDS h-buffer; wave-local fences instead of __syncthreads
__global__ __launch_bounds__(256) void k5_mlp(
    const unsigned short* __restrict__ z, const unsigned short* __restrict__ fc1T,
    const float* __restrict__ fc1_b, const unsigned short* __restrict__ fc2T,
    const float* __restrict__ fc2_b, float* __restrict__ out) {
  __shared__ __align__(16) unsigned short hl[4][32 * 70];
  int wv = threadIdx.x >> 6, lane = threadIdx.x & 63;
  int l15 = lane & 15, lhi = lane >> 4;
  int mbase = blockIdx.x * 128 + wv * 32;
  unsigned short* hw = hl[wv];
  bf16x8 afr[2][4];
#pragma unroll
  for (int mt = 0; mt < 2; ++mt)
#pragma unroll
    for (int ks = 0; ks < 4; ++ks)
      afr[mt][ks] = *(const bf16x8*)(z + (size_t)(mbase + mt * 16 + l15) * 128 + ks * 32 + lhi * 8);
  f32x4 oacc[2][8] = {};
  for (int ch = 0; ch < 8; ++ch) {
    f32x4 hacc[2][4] = {};
#pragma unroll
    for (int ks = 0; ks < 4; ++ks)
#pragma unroll
      for (int nt = 0; nt < 4; ++nt) {
        int hcol = ch * 64 + nt * 16 + l15;
        bf16x8 bfr = *(const bf16x8*)(fc1T + (size_t)hcol * 128 + ks * 32 + lhi * 8);
#pragma unroll
        for (int mt = 0; mt < 2; ++mt)
          hacc[mt][nt] = MFMA(afr[mt][ks], bfr, hacc[mt][nt]);
      }
#pragma unroll
    for (int mt = 0; mt < 2; ++mt)
#pragma unroll
      for (int nt = 0; nt < 4; ++nt)
#pragma unroll
        for (int j = 0; j < 4; ++j) {
          int r = mt * 16 + lhi * 4 + j;
          int hcol = ch * 64 + nt * 16 + l15;
          float hv = hacc[mt][nt][j] + fc1_b[hcol];
          float gv = 0.5f * hv * (1.0f + erff(hv * 0.70710678118654752f));
          hw[r * 70 + nt * 16 + l15] = f2bf(gv);
        }
    WAVE_LDS_FENCE();   // h writes -> h reads (wave-local)
#pragma unroll
    for (int ks = 0; ks < 2; ++ks) {
      bf16x8 a2[2];
#pragma unroll
      for (int mt = 0; mt < 2; ++mt)
        a2[mt] = *(const bf16x8*)(hw + (mt * 16 + l15) * 70 + ks * 32 + lhi * 8);
#pragma unroll
      for (int nt = 0; nt < 8; ++nt) {
        int ocol = nt * 16 + l15;
        bf16x8 bfr = *(const bf16x8*)(fc2T + (size_t)ocol * 512 + ch * 64 + ks * 32 + lhi * 8);
#pragma unroll
        for (int mt = 0; mt < 2; ++mt)
          oacc[mt][nt] = MFMA(a2[mt], bfr, oacc[mt][nt]);
      }
    }
    WAVE_LDS_FENCE();   // h reads done before next ch overwrites
  }
#pragma unroll
  for (int mt = 0; mt < 2; ++mt)
#pragma unroll
    for (int nt = 0; nt < 8; ++nt)
#pragma unroll
      for (int j = 0; j < 4; ++j) {
        int r = mbase + mt * 16 + lhi * 4 + j;
        out[(size_t)r * 128 + nt * 16 + l15] = oacc[mt][nt][j] + fc2_b[nt * 16 + l15];
      }
}

// ---------------------------------------------------------------------------
extern "C" void kernel_launch(void* const* d_in, const int* in_sizes, int n_in,
                              void* d_out, int out_size, void* d_ws, size_t ws_size,
                              hipStream_t stream) {
  const float* x      = (const float*)d_in[0];
  const float* mask   = (const float*)d_in[1];
  const int*   rel    = (const int*)d_in[2];
  const float* n1g    = (const float*)d_in[3];
  const float* n1b    = (const float*)d_in[4];
  const float* qkv_w  = (const float*)d_in[5];
  const float* qkv_b  = (const float*)d_in[6];
  const float* rpb    = (const float*)d_in[7];
  const float* proj_w = (const float*)d_in[8];
  const float* proj_b = (const float*)d_in[9];
  const float* n2g    = (const float*)d_in[10];
  const float* n2b    = (const float*)d_in[11];
  const float* fc1_w  = (const float*)d_in[12];
  const float* fc1_b  = (const float*)d_in[13];
  const float* fc2_w  = (const float*)d_in[14];
  const float* fc2_b  = (const float*)d_in[15];
  float* out = (float*)d_out;

  char* ws = (char*)d_ws;
  const size_t SZ = (size_t)NTOK * 128 * 2;            // 51,380,224 B
  unsigned short* win  = (unsigned short*)(ws);
  unsigned short* qb   = (unsigned short*)(ws + SZ);
  unsigned short* kb   = (unsigned short*)(ws + 2 * SZ);
  unsigned short* vb   = (unsigned short*)(ws + 3 * SZ);
  unsigned short* qkvT = (unsigned short*)(ws + 4 * SZ);
  unsigned short* projT = qkvT + 384 * 128;
  unsigned short* fc1T  = projT + 128 * 128;
  unsigned short* fc2T  = fc1T + 512 * 128;
  float* biasH = (float*)(fc2T + 128 * 512);           // 4*98*98 fp32
  unsigned short* ao = win;   // attn output reuses win buffer
  unsigned short* zb = qb;    // LN2 output reuses q buffer

  k0_prep<<<256, 256, 0, stream>>>(qkv_w, proj_w, fc1_w, fc2_w, rel, rpb,
                                   qkvT, projT, fc1T, fc2T, biasH);
  k1_ln_part<<<NTOK / 4, 256, 0, stream>>>(x, n1g, n1b, win);
  k2_qkv<<<NTOK / 16, 256, 0, stream>>>(win, qkvT, qkv_b, qb, kb, vb);
  k3_attn<<<NWIN * 4, 256, 0, stream>>>(qb, kb, vb, mask, biasH, ao);
  k4_proj_ln<<<NTOK / 64, 256, 0, stream>>>(ao, projT, proj_b, x, n2g, n2b, zb);
  k5_mlp<<<NTOK / 128, 256, 0, stream>>>(zb, fc1T, fc1_b, fc2T, fc2_b, out);
}

// Round 3
// 581.680 us; speedup vs baseline: 1.6379x; 1.2628x over previous
//
#include <hip/hip_runtime.h>
#include <hip/hip_bf16.h>

typedef __attribute__((ext_vector_type(8))) short bf16x8;
typedef __attribute__((ext_vector_type(4))) float f32x4;

#define MFMA(a,b,c) __builtin_amdgcn_mfma_f32_16x16x32_bf16((a),(b),(c),0,0,0)
#define WAVE_LDS_FENCE() do { asm volatile("s_waitcnt lgkmcnt(0)" ::: "memory"); \
                              __builtin_amdgcn_sched_barrier(0); } while (0)

static constexpr int NTOK = 8 * 8 * 56 * 56;   // 200704 tokens
static constexpr int NT   = 98;                // tokens per window
static constexpr int NWIN = 2048;              // total windows

__device__ __forceinline__ unsigned short f2bf(float f) {
  union { float f; unsigned u; } v; v.f = f;
  unsigned r = v.u + 0x7FFFu + ((v.u >> 16) & 1u);
  return (unsigned short)(r >> 16);
}

// ---------------- K0: weight transpose + bf16 cast + bias table ------------
__global__ __launch_bounds__(256) void k0_prep(
    const float* __restrict__ qkv_w, const float* __restrict__ proj_w,
    const float* __restrict__ fc1_w, const float* __restrict__ fc2_w,
    const int* __restrict__ rel, const float* __restrict__ rpb,
    unsigned short* __restrict__ qkvT, unsigned short* __restrict__ projT,
    unsigned short* __restrict__ fc1T, unsigned short* __restrict__ fc2T,
    float* __restrict__ biasH) {
  int idx = blockIdx.x * 256 + threadIdx.x;
  if (idx < 384 * 128) { int n = idx >> 7, k = idx & 127; qkvT[idx] = f2bf(qkv_w[k * 384 + n]); }
  if (idx < 128 * 128) { int n = idx >> 7, k = idx & 127; projT[idx] = f2bf(proj_w[k * 128 + n]); }
  if (idx < 512 * 128) { int n = idx >> 7, k = idx & 127; fc1T[idx] = f2bf(fc1_w[k * 512 + n]); }
  if (idx < 128 * 512) { int n = idx >> 9, k = idx & 511; fc2T[idx] = f2bf(fc2_w[k * 128 + n]); }
  if (idx < 4 * NT * NT) {
    int h = idx / (NT * NT), r = idx % (NT * NT);
    biasH[idx] = rpb[rel[r] * 4 + h];
  }
}

// ---------------- K1: LN1 + cyclic shift + window partition ----------------
__global__ __launch_bounds__(256) void k1_ln_part(
    const float* __restrict__ x, const float* __restrict__ g,
    const float* __restrict__ b, unsigned short* __restrict__ win) {
  int wv = threadIdx.x >> 6, lane = threadIdx.x & 63;
  int t = blockIdx.x * 4 + wv;
  int widx = t / NT, n = t - widx * NT;
  int bb = widx >> 8, wb = widx & 255;
  int dW = wb >> 6, hW = (wb >> 3) & 7, wW = wb & 7;
  int dr = n / 49, rem = n - dr * 49, hr = rem / 7, wr = rem - hr * 7;
  int ds = (dW * 2 + dr + 1) & 7;
  int hs = hW * 7 + hr + 3; if (hs >= 56) hs -= 56;
  int wsv = wW * 7 + wr + 3; if (wsv >= 56) wsv -= 56;
  size_t srow = ((size_t)(bb * 8 + ds) * 56 + hs) * 56 + wsv;
  const float2 v2 = *(const float2*)(x + srow * 128 + lane * 2);
  float s = v2.x + v2.y, ss = v2.x * v2.x + v2.y * v2.y;
#pragma unroll
  for (int m = 1; m < 64; m <<= 1) { s += __shfl_xor(s, m); ss += __shfl_xor(ss, m); }
  float mu = s * (1.f / 128.f);
  float var = ss * (1.f / 128.f) - mu * mu;
  float inv = rsqrtf(var + 1e-5f);
  float g0 = g[lane * 2], g1 = g[lane * 2 + 1];
  float b0 = b[lane * 2], b1 = b[lane * 2 + 1];
  unsigned short o0 = f2bf((v2.x - mu) * inv * g0 + b0);
  unsigned short o1 = f2bf((v2.y - mu) * inv * g1 + b1);
  *(unsigned*)(win + (size_t)t * 128 + lane * 2) = (unsigned)o0 | ((unsigned)o1 << 16);
}

// ---------------- K2: QKV GEMM [200704,128]@[128,384] ----------------------
__global__ __launch_bounds__(256) void k2_qkv(
    const unsigned short* __restrict__ win, const unsigned short* __restrict__ qkvT,
    const float* __restrict__ qkv_b,
    unsigned short* __restrict__ q, unsigned short* __restrict__ k,
    unsigned short* __restrict__ v) {
  int wv = threadIdx.x >> 6, lane = threadIdx.x & 63;
  int l15 = lane & 15, lhi = lane >> 4;
  int mbase = blockIdx.x * 16;
  const unsigned short* arow = win + (size_t)(mbase + l15) * 128 + lhi * 8;
  bf16x8 afr[4];
#pragma unroll
  for (int ks = 0; ks < 4; ++ks) afr[ks] = *(const bf16x8*)(arow + ks * 32);
  int nt0 = wv * 6;
  f32x4 acc[6] = {};
#pragma unroll
  for (int ks = 0; ks < 4; ++ks)
#pragma unroll
    for (int nt = 0; nt < 6; ++nt) {
      int col = (nt0 + nt) * 16 + l15;
      bf16x8 bfr = *(const bf16x8*)(qkvT + (size_t)col * 128 + ks * 32 + lhi * 8);
      acc[nt] = MFMA(afr[ks], bfr, acc[nt]);
    }
#pragma unroll
  for (int nt = 0; nt < 6; ++nt) {
    int col = (nt0 + nt) * 16 + l15;
    int which = col >> 7, head = (col >> 5) & 3, hd = col & 31;
    unsigned short* outb = which == 0 ? q : (which == 1 ? k : v);
    float scale = which == 0 ? 0.17677669529663687f : 1.0f;
    float bias = qkv_b[col];
#pragma unroll
    for (int j = 0; j < 4; ++j) {
      int row = mbase + lhi * 4 + j;
      int widx = row / NT, n = row - widx * NT;
      float val = (acc[nt][j] + bias) * scale;
      outb[(size_t)((widx * 4 + head) * NT + n) * 32 + hd] = f2bf(val);
    }
  }
}

// ---------------- K3: window attention, one block per (window, head) -------
__global__ __launch_bounds__(256) void k3_attn(
    const unsigned short* __restrict__ q, const unsigned short* __restrict__ kk,
    const unsigned short* __restrict__ vv, const float* __restrict__ mask,
    const float* __restrict__ biasH, unsigned short* __restrict__ out) {
  __shared__ __align__(16) unsigned short Vt[32 * 140];
  __shared__ __align__(16) unsigned short Pw[4][16 * 140];
  int bid = blockIdx.x;
  int widx = bid >> 2, head = bid & 3;
  int wb = widx & 255;
  size_t base = (size_t)(widx * 4 + head) * NT * 32;
  int tid = threadIdx.x, wv = tid >> 6, lane = tid & 63;
  int l15 = lane & 15, lhi = lane >> 4;

  for (int idx = tid; idx < NT * 32; idx += 256) {
    int j = idx >> 5, d = idx & 31;
    Vt[d * 140 + j] = vv[base + idx];
  }
  for (int idx = tid; idx < 32 * 30; idx += 256) {
    int d = idx / 30, j = 98 + idx % 30;
    Vt[d * 140 + j] = 0;
  }
  __syncthreads();

  const float* maskw = mask + (size_t)wb * NT * NT;
  const float* biash = biasH + head * NT * NT;
  unsigned short* P = Pw[wv];

  for (int mt = wv; mt < 7; mt += 4) {
    int mb = mt * 16;
    bf16x8 afr = *(const bf16x8*)(q + base + (size_t)(mb + l15) * 32 + lhi * 8);
    f32x4 sfr[7];
#pragma unroll
    for (int nt = 0; nt < 7; ++nt) {
      bf16x8 bfr = *(const bf16x8*)(kk + base + (size_t)(nt * 16 + l15) * 32 + lhi * 8);
      f32x4 zz = {};
      sfr[nt] = MFMA(afr, bfr, zz);
    }
#pragma unroll
    for (int j = 0; j < 4; ++j) {
      int i = mb + lhi * 4 + j;
      int ic = i < 97 ? i : 97;
      float sv[7];
#pragma unroll
      for (int nt = 0; nt < 7; ++nt) {
        int colc = nt * 16 + l15;
        int jc = colc < 97 ? colc : 97;
        float s = fminf(fmaxf(sfr[nt][j], -1e4f), 1e4f);
        float bm = biash[ic * NT + jc] + maskw[ic * NT + jc];
        sv[nt] = (i < NT && colc < NT) ? (s + bm) : -1e30f;
      }
      float mx = sv[0];
#pragma unroll
      for (int nt = 1; nt < 7; ++nt) mx = fmaxf(mx, sv[nt]);
#pragma unroll
      for (int m2 = 1; m2 < 16; m2 <<= 1) mx = fmaxf(mx, __shfl_xor(mx, m2));
      float sum = 0.f, p[7];
#pragma unroll
      for (int nt = 0; nt < 7; ++nt) { p[nt] = __expf(sv[nt] - mx); sum += p[nt]; }
#pragma unroll
      for (int m2 = 1; m2 < 16; m2 <<= 1) sum += __shfl_xor(sum, m2);
      float inv = 1.0f / sum;
      int iloc = lhi * 4 + j;
#pragma unroll
      for (int nt = 0; nt < 7; ++nt)
        P[iloc * 140 + nt * 16 + l15] = f2bf(p[nt] * inv);
      P[iloc * 140 + 112 + l15] = 0;
    }
    WAVE_LDS_FENCE();

    f32x4 ofr[2] = {};
#pragma unroll
    for (int ks = 0; ks < 4; ++ks) {
      bf16x8 pafr = *(const bf16x8*)(P + l15 * 140 + ks * 32 + lhi * 8);
#pragma unroll
      for (int nt = 0; nt < 2; ++nt) {
        bf16x8 bfr = *(const bf16x8*)(Vt + (nt * 16 + l15) * 140 + ks * 32 + lhi * 8);
        ofr[nt] = MFMA(pafr, bfr, ofr[nt]);
      }
    }
#pragma unroll
    for (int nt = 0; nt < 2; ++nt)
#pragma unroll
      for (int j = 0; j < 4; ++j) {
        int n = mb + lhi * 4 + j;
        if (n < NT) {
          int d = nt * 16 + l15;
          out[(size_t)(widx * NT + n) * 128 + head * 32 + d] = f2bf(ofr[nt][j]);
        }
      }
    WAVE_LDS_FENCE();
  }
}

// ---------------- K4: proj + reverse/unshift + residual + LN2 --------------
__global__ __launch_bounds__(256) void k4_proj_ln(
    const unsigned short* __restrict__ ao, const unsigned short* __restrict__ projT,
    const float* __restrict__ proj_b, const float* __restrict__ x,
    const float* __restrict__ g2, const float* __restrict__ b2,
    unsigned short* __restrict__ z) {
  int wv = threadIdx.x >> 6, lane = threadIdx.x & 63;
  int l15 = lane & 15, lhi = lane >> 4;
  int mbase = blockIdx.x * 64 + wv * 16;
  const unsigned short* arow = ao + (size_t)(mbase + l15) * 128 + lhi * 8;
  bf16x8 afr[4];
#pragma unroll
  for (int ks = 0; ks < 4; ++ks) afr[ks] = *(const bf16x8*)(arow + ks * 32);
  f32x4 acc[8] = {};
#pragma unroll
  for (int ks = 0; ks < 4; ++ks)
#pragma unroll
    for (int nt = 0; nt < 8; ++nt) {
      bf16x8 bfr = *(const bf16x8*)(projT + (size_t)(nt * 16 + l15) * 128 + ks * 32 + lhi * 8);
      acc[nt] = MFMA(afr[ks], bfr, acc[nt]);
    }
#pragma unroll
  for (int j = 0; j < 4; ++j) {
    int t = mbase + lhi * 4 + j;
    int widx = t / NT, n = t - widx * NT;
    int bb = widx >> 8, wb = widx & 255;
    int dW = wb >> 6, hW = (wb >> 3) & 7, wW = wb & 7;
    int dr = n / 49, rem = n - dr * 49, hr = rem / 7, wr = rem - hr * 7;
    int d = (dW * 2 + dr + 1) & 7;
    int h = hW * 7 + hr + 3; if (h >= 56) h -= 56;
    int w = wW * 7 + wr + 3; if (w >= 56) w -= 56;
    size_t srow = ((size_t)(bb * 8 + d) * 56 + h) * 56 + w;
    float vals[8], s = 0.f, ss = 0.f;
#pragma unroll
    for (int nt = 0; nt < 8; ++nt) {
      int colc = nt * 16 + l15;
      float val = acc[nt][j] + proj_b[colc] + x[srow * 128 + colc];
      vals[nt] = val; s += val; ss += val * val;
    }
#pragma unroll
    for (int m2 = 1; m2 < 16; m2 <<= 1) { s += __shfl_xor(s, m2); ss += __shfl_xor(ss, m2); }
    float mu = s * (1.f / 128.f);
    float var = ss * (1.f / 128.f) - mu * mu;
    float inv = rsqrtf(var + 1e-5f);
#pragma unroll
    for (int nt = 0; nt < 8; ++nt) {
      int colc = nt * 16 + l15;
      z[srow * 128 + colc] = f2bf((vals[nt] - mu) * inv * g2[colc] + b2[colc]);
    }
  }
}

// ---------------- K5: MLP fc1 + GELU + fc2, LDS-staged weights -------------
// block = 4 waves, 128 rows (32/wave); hidden chunked by 64.
// Per chunk: cooperative stage fc1T[64x128]->wsA (pitch 132), fc2T[128x64]->wsB
// (pitch 68); all B-fragments via ds_read_b128. h bounce per-wave (pitch 70).
__global__ __launch_bounds__(256, 2) void k5_mlp(
    const unsigned short* __restrict__ z, const unsigned short* __restrict__ fc1T,
    const float* __restrict__ fc1_b, const unsigned short* __restrict__ fc2T,
    const float* __restrict__ fc2_b, float* __restrict__ out) {
  __shared__ __align__(16) unsigned short wsA[64 * 132];   // 16896 B
  __shared__ __align__(16) unsigned short wsB[128 * 68];   // 17408 B
  __shared__ __align__(16) unsigned short hl[4][32 * 70];  // 17920 B
  int tid = threadIdx.x;
  int wv = tid >> 6, lane = tid & 63;
  int l15 = lane & 15, lhi = lane >> 4;
  int mbase = blockIdx.x * 128 + wv * 32;
  unsigned short* hw = hl[wv];

  bf16x8 afr[2][4];
#pragma unroll
  for (int mt = 0; mt < 2; ++mt)
#pragma unroll
    for (int ks = 0; ks < 4; ++ks)
      afr[mt][ks] = *(const bf16x8*)(z + (size_t)(mbase + mt * 16 + l15) * 128 + ks * 32 + lhi * 8);

  f32x4 oacc[2][8] = {};
  for (int ch = 0; ch < 8; ++ch) {
    __syncthreads();   // previous chunk's LDS reads done before restage
    // stage fc1 chunk: 64 rows x 128 k  (coalesced 1KB per instruction)
    const unsigned short* srcA = fc1T + (size_t)ch * 64 * 128;
#pragma unroll
    for (int u = 0; u < 4; ++u) {
      int flat = u * 2048 + tid * 8;
      int r = flat >> 7, c = flat & 127;
      *(bf16x8*)(&wsA[r * 132 + c]) = *(const bf16x8*)(srcA + flat);
    }
    // stage fc2 chunk: 128 ocols x 64 k
#pragma unroll
    for (int u = 0; u < 4; ++u) {
      int flat = u * 2048 + tid * 8;
      int oc = flat >> 6, kc = flat & 63;
      *(bf16x8*)(&wsB[oc * 68 + kc]) = *(const bf16x8*)(fc2T + (size_t)oc * 512 + ch * 64 + kc);
    }
    __syncthreads();

    // fc1: h[32 x 64] per wave
    f32x4 hacc[2][4] = {};
#pragma unroll
    for (int ks = 0; ks < 4; ++ks)
#pragma unroll
      for (int nt = 0; nt < 4; ++nt) {
        bf16x8 bfr = *(const bf16x8*)(&wsA[(nt * 16 + l15) * 132 + ks * 32 + lhi * 8]);
#pragma unroll
        for (int mt = 0; mt < 2; ++mt)
          hacc[mt][nt] = MFMA(afr[mt][ks], bfr, hacc[mt][nt]);
      }
#pragma unroll
    for (int mt = 0; mt < 2; ++mt)
#pragma unroll
      for (int nt = 0; nt < 4; ++nt)
#pragma unroll
        for (int j = 0; j < 4; ++j) {
          int r = mt * 16 + lhi * 4 + j;
          int hcol = ch * 64 + nt * 16 + l15;
          float hv = hacc[mt][nt][j] + fc1_b[hcol];
          float gv = 0.5f * hv * (1.0f + erff(hv * 0.70710678118654752f));
          hw[r * 70 + nt * 16 + l15] = f2bf(gv);
        }
    WAVE_LDS_FENCE();   // h writes -> h reads (wave-local)

    // fc2: accumulate
#pragma unroll
    for (int ks = 0; ks < 2; ++ks) {
      bf16x8 a2[2];
#pragma unroll
      for (int mt = 0; mt < 2; ++mt)
        a2[mt] = *(const bf16x8*)(&hw[(mt * 16 + l15) * 70 + ks * 32 + lhi * 8]);
#pragma unroll
      for (int nt = 0; nt < 8; ++nt) {
        bf16x8 bfr = *(const bf16x8*)(&wsB[(nt * 16 + l15) * 68 + ks * 32 + lhi * 8]);
#pragma unroll
        for (int mt = 0; mt < 2; ++mt)
          oacc[mt][nt] = MFMA(a2[mt], bfr, oacc[mt][nt]);
      }
    }
    WAVE_LDS_FENCE();   // h reads done before next ch overwrites
  }
#pragma unroll
  for (int mt = 0; mt < 2; ++mt)
#pragma unroll
    for (int nt = 0; nt < 8; ++nt)
#pragma unroll
      for (int j = 0; j < 4; ++j) {
        int r = mbase + mt * 16 + lhi * 4 + j;
        out[(size_t)r * 128 + nt * 16 + l15] = oacc[mt][nt][j] + fc2_b[nt * 16 + l15];
      }
}

// ---------------------------------------------------------------------------
extern "C" void kernel_launch(void* const* d_in, const int* in_sizes, int n_in,
                              void* d_out, int out_size, void* d_ws, size_t ws_size,
                              hipStream_t stream) {
  const float* x      = (const float*)d_in[0];
  const float* mask   = (const float*)d_in[1];
  const int*   rel    = (const int*)d_in[2];
  const float* n1g    = (const float*)d_in[3];
  const float* n1b    = (const float*)d_in[4];
  const float* qkv_w  = (const float*)d_in[5];
  const float* qkv_b  = (const float*)d_in[6];
  const float* rpb    = (const float*)d_in[7];
  const float* proj_w = (const float*)d_in[8];
  const float* proj_b = (const float*)d_in[9];
  const float* n2g    = (const float*)d_in[10];
  const float* n2b    = (const float*)d_in[11];
  const float* fc1_w  = (const float*)d_in[12];
  const float* fc1_b  = (const float*)d_in[13];
  const float* fc2_w  = (const float*)d_in[14];
  const float* fc2_b  = (const float*)d_in[15];
  float* out = (float*)d_out;

  char* ws = (char*)d_ws;
  const size_t SZ = (size_t)NTOK * 128 * 2;
  unsigned short* win  = (unsigned short*)(ws);
  unsigned short* qb   = (unsigned short*)(ws + SZ);
  unsigned short* kb   = (unsigned short*)(ws + 2 * SZ);
  unsigned short* vb   = (unsigned short*)(ws + 3 * SZ);
  unsigned short* qkvT = (unsigned short*)(ws + 4 * SZ);
  unsigned short* projT = qkvT + 384 * 128;
  unsigned short* fc1T  = projT + 128 * 128;
  unsigned short* fc2T  = fc1T + 512 * 128;
  float* biasH = (float*)(fc2T + 128 * 512);
  unsigned short* ao = win;
  unsigned short* zb = qb;

  k0_prep<<<256, 256, 0, stream>>>(qkv_w, proj_w, fc1_w, fc2_w, rel, rpb,
                                   qkvT, projT, fc1T, fc2T, biasH);
  k1_ln_part<<<NTOK / 4, 256, 0, stream>>>(x, n1g, n1b, win);
  k2_qkv<<<NTOK / 16, 256, 0, stream>>>(win, qkvT, qkv_b, qb, kb, vb);
  k3_attn<<<NWIN * 4, 256, 0, stream>>>(qb, kb, vb, mask, biasH, ao);
  k4_proj_ln<<<NTOK / 64, 256, 0, stream>>>(ao, projT, proj_b, x, n2g, n2b, zb);
  k5_mlp<<<NTOK / 128, 256, 0, stream>>>(zb, fc1T, fc1_b, fc2T, fc2_b, out);
}

// Round 4
// 430.553 us; speedup vs baseline: 2.2128x; 1.3510x over previous
//
#include <hip/hip_runtime.h>
#include <hip/hip_bf16.h>

typedef __attribute__((ext_vector_type(8))) short bf16x8;
typedef __attribute__((ext_vector_type(4))) float f32x4;

#define MFMA(a,b,c) __builtin_amdgcn_mfma_f32_16x16x32_bf16((a),(b),(c),0,0,0)
#define WAVE_LDS_FENCE() do { asm volatile("s_waitcnt lgkmcnt(0)" ::: "memory"); \
                              __builtin_amdgcn_sched_barrier(0); } while (0)

static constexpr int NTOK = 8 * 8 * 56 * 56;   // 200704 tokens
static constexpr int NT   = 98;                // tokens per window
static constexpr int NWIN = 2048;              // total windows
static constexpr int NN   = NT * NT;           // 9604

__device__ __forceinline__ unsigned short f2bf(float f) {
  union { float f; unsigned u; } v; v.f = f;
  unsigned r = v.u + 0x7FFFu + ((v.u >> 16) & 1u);
  return (unsigned short)(r >> 16);
}
__device__ __forceinline__ float bf2f(unsigned short s) {
  union { unsigned u; float f; } v; v.u = ((unsigned)s) << 16; return v.f;
}

// ---------------- K0: weight transpose + bf16 cast -------------------------
__global__ __launch_bounds__(256) void k0_prep(
    const float* __restrict__ qkv_w, const float* __restrict__ proj_w,
    const float* __restrict__ fc1_w, const float* __restrict__ fc2_w,
    unsigned short* __restrict__ qkvT, unsigned short* __restrict__ projT,
    unsigned short* __restrict__ fc1T, unsigned short* __restrict__ fc2T) {
  int idx = blockIdx.x * 256 + threadIdx.x;
  if (idx < 384 * 128) { int n = idx >> 7, k = idx & 127; qkvT[idx] = f2bf(qkv_w[k * 384 + n]); }
  if (idx < 128 * 128) { int n = idx >> 7, k = idx & 127; projT[idx] = f2bf(proj_w[k * 128 + n]); }
  if (idx < 512 * 128) { int n = idx >> 7, k = idx & 127; fc1T[idx] = f2bf(fc1_w[k * 512 + n]); }
  if (idx < 128 * 512) { int n = idx >> 9, k = idx & 511; fc2T[idx] = f2bf(fc2_w[k * 128 + n]); }
}

// ---------------- K0b: combined bias+mask table, bf16 ----------------------
// cmb[head][wb][i][j] = rpb[rel[i][j]][head] + mask[wb][i][j]
__global__ __launch_bounds__(256) void k0b_cmb(
    const int* __restrict__ rel, const float* __restrict__ rpb,
    const float* __restrict__ mask, unsigned short* __restrict__ cmb) {
  int idx = blockIdx.x * 256 + threadIdx.x;
  if (idx >= 4 * 256 * NN) return;
  int h = idx / (256 * NN);
  int rem = idx - h * 256 * NN;
  int wb = rem / NN, r = rem - wb * NN;
  cmb[idx] = f2bf(rpb[rel[r] * 4 + h] + mask[(size_t)wb * NN + r]);
}

// ---------------- K1: LN1 + cyclic shift + window partition ----------------
__global__ __launch_bounds__(256) void k1_ln_part(
    const float* __restrict__ x, const float* __restrict__ g,
    const float* __restrict__ b, unsigned short* __restrict__ win) {
  int wv = threadIdx.x >> 6, lane = threadIdx.x & 63;
  int t = blockIdx.x * 4 + wv;
  int widx = t / NT, n = t - widx * NT;
  int bb = widx >> 8, wb = widx & 255;
  int dW = wb >> 6, hW = (wb >> 3) & 7, wW = wb & 7;
  int dr = n / 49, rem = n - dr * 49, hr = rem / 7, wr = rem - hr * 7;
  int ds = (dW * 2 + dr + 1) & 7;
  int hs = hW * 7 + hr + 3; if (hs >= 56) hs -= 56;
  int wsv = wW * 7 + wr + 3; if (wsv >= 56) wsv -= 56;
  size_t srow = ((size_t)(bb * 8 + ds) * 56 + hs) * 56 + wsv;
  const float2 v2 = *(const float2*)(x + srow * 128 + lane * 2);
  float s = v2.x + v2.y, ss = v2.x * v2.x + v2.y * v2.y;
#pragma unroll
  for (int m = 1; m < 64; m <<= 1) { s += __shfl_xor(s, m); ss += __shfl_xor(ss, m); }
  float mu = s * (1.f / 128.f);
  float var = ss * (1.f / 128.f) - mu * mu;
  float inv = rsqrtf(var + 1e-5f);
  float g0 = g[lane * 2], g1 = g[lane * 2 + 1];
  float b0 = b[lane * 2], b1 = b[lane * 2 + 1];
  unsigned short o0 = f2bf((v2.x - mu) * inv * g0 + b0);
  unsigned short o1 = f2bf((v2.y - mu) * inv * g1 + b1);
  *(unsigned*)(win + (size_t)t * 128 + lane * 2) = (unsigned)o0 | ((unsigned)o1 << 16);
}

// ---------------- K2: QKV GEMM, LDS-staged weights + reg prefetch ----------
// block = 128 rows (4 waves x 32); 6 chunks of 64 cols
__global__ __launch_bounds__(256, 4) void k2_qkv(
    const unsigned short* __restrict__ win, const unsigned short* __restrict__ qkvT,
    const float* __restrict__ qkv_b,
    unsigned short* __restrict__ q, unsigned short* __restrict__ k,
    unsigned short* __restrict__ v) {
  __shared__ __align__(16) unsigned short wsW[64 * 136];   // 17408 B
  int tid = threadIdx.x, wv = tid >> 6, lane = tid & 63;
  int l15 = lane & 15, lhi = lane >> 4;
  int mbase = blockIdx.x * 128 + wv * 32;

  bf16x8 afr[2][4];
#pragma unroll
  for (int mt = 0; mt < 2; ++mt)
#pragma unroll
    for (int ks = 0; ks < 4; ++ks)
      afr[mt][ks] = *(const bf16x8*)(win + (size_t)(mbase + mt * 16 + l15) * 128 + ks * 32 + lhi * 8);

  int rbase[2][4];
#pragma unroll
  for (int mt = 0; mt < 2; ++mt)
#pragma unroll
    for (int j = 0; j < 4; ++j) {
      int r = mbase + mt * 16 + lhi * 4 + j;
      int widx = r / NT, n = r - widx * NT;
      rbase[mt][j] = widx * 392 + n;
    }

  bf16x8 pf[4];
#pragma unroll
  for (int u = 0; u < 4; ++u) pf[u] = *(const bf16x8*)(qkvT + u * 2048 + tid * 8);

  for (int ch = 0; ch < 6; ++ch) {
#pragma unroll
    for (int u = 0; u < 4; ++u) {
      int flat = u * 2048 + tid * 8;
      *(bf16x8*)(&wsW[(flat >> 7) * 136 + (flat & 127)]) = pf[u];
    }
    __syncthreads();
    if (ch < 5) {
#pragma unroll
      for (int u = 0; u < 4; ++u)
        pf[u] = *(const bf16x8*)(qkvT + (ch + 1) * 8192 + u * 2048 + tid * 8);
    }
    f32x4 acc[2][4] = {};
#pragma unroll
    for (int ks = 0; ks < 4; ++ks)
#pragma unroll
      for (int nt = 0; nt < 4; ++nt) {
        bf16x8 bfr = *(const bf16x8*)(&wsW[(nt * 16 + l15) * 136 + ks * 32 + lhi * 8]);
#pragma unroll
        for (int mt = 0; mt < 2; ++mt)
          acc[mt][nt] = MFMA(afr[mt][ks], bfr, acc[mt][nt]);
      }
#pragma unroll
    for (int nt = 0; nt < 4; ++nt) {
      int col = ch * 64 + nt * 16 + l15;
      int which = col >> 7, head = (col >> 5) & 3, hd = col & 31;
      unsigned short* outb = which == 0 ? q : (which == 1 ? k : v);
      float scale = which == 0 ? 0.17677669529663687f : 1.0f;
      float bias = qkv_b[col];
#pragma unroll
      for (int mt = 0; mt < 2; ++mt)
#pragma unroll
        for (int j = 0; j < 4; ++j) {
          float val = (acc[mt][nt][j] + bias) * scale;
          outb[(size_t)(rbase[mt][j] + head * 98) * 32 + hd] = f2bf(val);
        }
    }
    __syncthreads();
  }
}

// ---------------- K3: window attention, one block per (window, head) -------
__global__ __launch_bounds__(256) void k3_attn(
    const unsigned short* __restrict__ q, const unsigned short* __restrict__ kk,
    const unsigned short* __restrict__ vv, const unsigned short* __restrict__ cmb,
    unsigned short* __restrict__ out) {
  __shared__ __align__(16) unsigned short Vt[32 * 140];
  __shared__ __align__(16) unsigned short Pw[4][16 * 140];
  int bid = blockIdx.x;
  int widx = bid >> 2, head = bid & 3;
  int wb = widx & 255;
  size_t base = (size_t)(widx * 4 + head) * NT * 32;
  int tid = threadIdx.x, wv = tid >> 6, lane = tid & 63;
  int l15 = lane & 15, lhi = lane >> 4;

  for (int idx = tid; idx < NT * 32; idx += 256) {
    int j = idx >> 5, d = idx & 31;
    Vt[d * 140 + j] = vv[base + idx];
  }
  for (int idx = tid; idx < 32 * 30; idx += 256) {
    int d = idx / 30, j = 98 + idx % 30;
    Vt[d * 140 + j] = 0;
  }
  __syncthreads();

  const unsigned short* cw = cmb + ((size_t)(head << 8) + wb) * NN;
  unsigned short* P = Pw[wv];

  for (int mt = wv; mt < 7; mt += 4) {
    int mb = mt * 16;
    bf16x8 afr = *(const bf16x8*)(q + base + (size_t)(mb + l15) * 32 + lhi * 8);
    f32x4 sfr[7];
#pragma unroll
    for (int nt = 0; nt < 7; ++nt) {
      bf16x8 bfr = *(const bf16x8*)(kk + base + (size_t)(nt * 16 + l15) * 32 + lhi * 8);
      f32x4 zz = {};
      sfr[nt] = MFMA(afr, bfr, zz);
    }
#pragma unroll
    for (int j = 0; j < 4; ++j) {
      int i = mb + lhi * 4 + j;
      int ic = i < 97 ? i : 97;
      float sv[7];
#pragma unroll
      for (int nt = 0; nt < 7; ++nt) {
        int colc = nt * 16 + l15;
        int jc = colc < 97 ? colc : 97;
        float s = fminf(fmaxf(sfr[nt][j], -1e4f), 1e4f);
        float bm = bf2f(cw[ic * NT + jc]);
        sv[nt] = (i < NT && colc < NT) ? (s + bm) : -1e30f;
      }
      float mx = sv[0];
#pragma unroll
      for (int nt = 1; nt < 7; ++nt) mx = fmaxf(mx, sv[nt]);
#pragma unroll
      for (int m2 = 1; m2 < 16; m2 <<= 1) mx = fmaxf(mx, __shfl_xor(mx, m2));
      float sum = 0.f, p[7];
#pragma unroll
      for (int nt = 0; nt < 7; ++nt) { p[nt] = __expf(sv[nt] - mx); sum += p[nt]; }
#pragma unroll
      for (int m2 = 1; m2 < 16; m2 <<= 1) sum += __shfl_xor(sum, m2);
      float inv = 1.0f / sum;
      int iloc = lhi * 4 + j;
#pragma unroll
      for (int nt = 0; nt < 7; ++nt)
        P[iloc * 140 + nt * 16 + l15] = f2bf(p[nt] * inv);
      P[iloc * 140 + 112 + l15] = 0;
    }
    WAVE_LDS_FENCE();

    f32x4 ofr[2] = {};
#pragma unroll
    for (int ks = 0; ks < 4; ++ks) {
      bf16x8 pafr = *(const bf16x8*)(P + l15 * 140 + ks * 32 + lhi * 8);
#pragma unroll
      for (int nt = 0; nt < 2; ++nt) {
        bf16x8 bfr = *(const bf16x8*)(Vt + (nt * 16 + l15) * 140 + ks * 32 + lhi * 8);
        ofr[nt] = MFMA(pafr, bfr, ofr[nt]);
      }
    }
#pragma unroll
    for (int nt = 0; nt < 2; ++nt)
#pragma unroll
      for (int j = 0; j < 4; ++j) {
        int n = mb + lhi * 4 + j;
        if (n < NT) {
          int d = nt * 16 + l15;
          out[(size_t)(widx * NT + n) * 128 + head * 32 + d] = f2bf(ofr[nt][j]);
        }
      }
    WAVE_LDS_FENCE();
  }
}

// ---------------- K4: proj + reverse/unshift + residual + LN2 --------------
// projT staged ONCE in LDS; block = 128 rows (4 waves x 32)
__global__ __launch_bounds__(256, 3) void k4_proj_ln(
    const unsigned short* __restrict__ ao, const unsigned short* __restrict__ projT,
    const float* __restrict__ proj_b, const float* __restrict__ x,
    const float* __restrict__ g2, const float* __restrict__ b2,
    unsigned short* __restrict__ z) {
  __shared__ __align__(16) unsigned short wsW[128 * 136];   // 34816 B
  int tid = threadIdx.x, wv = tid >> 6, lane = tid & 63;
  int l15 = lane & 15, lhi = lane >> 4;
  int mbase = blockIdx.x * 128 + wv * 32;

#pragma unroll
  for (int u = 0; u < 8; ++u) {
    int flat = u * 2048 + tid * 8;
    *(bf16x8*)(&wsW[(flat >> 7) * 136 + (flat & 127)]) = *(const bf16x8*)(projT + flat);
  }
  bf16x8 afr[2][4];
#pragma unroll
  for (int mt = 0; mt < 2; ++mt)
#pragma unroll
    for (int ks = 0; ks < 4; ++ks)
      afr[mt][ks] = *(const bf16x8*)(ao + (size_t)(mbase + mt * 16 + l15) * 128 + ks * 32 + lhi * 8);
  __syncthreads();

  f32x4 acc[2][8] = {};
#pragma unroll
  for (int ks = 0; ks < 4; ++ks)
#pragma unroll
    for (int nt = 0; nt < 8; ++nt) {
      bf16x8 bfr = *(const bf16x8*)(&wsW[(nt * 16 + l15) * 136 + ks * 32 + lhi * 8]);
#pragma unroll
      for (int mt = 0; mt < 2; ++mt)
        acc[mt][nt] = MFMA(afr[mt][ks], bfr, acc[mt][nt]);
    }

#pragma unroll
  for (int mt = 0; mt < 2; ++mt)
#pragma unroll
    for (int j = 0; j < 4; ++j) {
      int t = mbase + mt * 16 + lhi * 4 + j;
      int widx = t / NT, n = t - widx * NT;
      int bb = widx >> 8, wb = widx & 255;
      int dW = wb >> 6, hW = (wb >> 3) & 7, wW = wb & 7;
      int dr = n / 49, rem = n - dr * 49, hr = rem / 7, wr = rem - hr * 7;
      int d = (dW * 2 + dr + 1) & 7;
      int h = hW * 7 + hr + 3; if (h >= 56) h -= 56;
      int w = wW * 7 + wr + 3; if (w >= 56) w -= 56;
      size_t srow = ((size_t)(bb * 8 + d) * 56 + h) * 56 + w;
      float vals[8], s = 0.f, ss = 0.f;
#pragma unroll
      for (int nt = 0; nt < 8; ++nt) {
        int colc = nt * 16 + l15;
        float val = acc[mt][nt][j] + proj_b[colc] + x[srow * 128 + colc];
        vals[nt] = val; s += val; ss += val * val;
      }
#pragma unroll
      for (int m2 = 1; m2 < 16; m2 <<= 1) { s += __shfl_xor(s, m2); ss += __shfl_xor(ss, m2); }
      float mu = s * (1.f / 128.f);
      float var = ss * (1.f / 128.f) - mu * mu;
      float inv = rsqrtf(var + 1e-5f);
#pragma unroll
      for (int nt = 0; nt < 8; ++nt) {
        int colc = nt * 16 + l15;
        z[srow * 128 + colc] = f2bf((vals[nt] - mu) * inv * g2[colc] + b2[colc]);
      }
    }
}

// ---------------- K5: MLP fc1 + tanh-GELU + fc2, staged + prefetch ---------
__global__ __launch_bounds__(256, 2) void k5_mlp(
    const unsigned short* __restrict__ z, const unsigned short* __restrict__ fc1T,
    const float* __restrict__ fc1_b, const unsigned short* __restrict__ fc2T,
    const float* __restrict__ fc2_b, float* __restrict__ out) {
  __shared__ __align__(16) unsigned short wsA[64 * 136];   // 17408 B
  __shared__ __align__(16) unsigned short wsB[128 * 72];   // 18432 B
  __shared__ __align__(16) unsigned short hl[4][32 * 72];  // 18432 B
  int tid = threadIdx.x, wv = tid >> 6, lane = tid & 63;
  int l15 = lane & 15, lhi = lane >> 4;
  int mbase = blockIdx.x * 128 + wv * 32;
  unsigned short* hw = hl[wv];

  bf16x8 afr[2][4];
#pragma unroll
  for (int mt = 0; mt < 2; ++mt)
#pragma unroll
    for (int ks = 0; ks < 4; ++ks)
      afr[mt][ks] = *(const bf16x8*)(z + (size_t)(mbase + mt * 16 + l15) * 128 + ks * 32 + lhi * 8);

  bf16x8 pfA[4], pfB[4];
#pragma unroll
  for (int u = 0; u < 4; ++u) pfA[u] = *(const bf16x8*)(fc1T + u * 2048 + tid * 8);
#pragma unroll
  for (int u = 0; u < 4; ++u) {
    int flat = u * 2048 + tid * 8;
    pfB[u] = *(const bf16x8*)(fc2T + (size_t)(flat >> 6) * 512 + (flat & 63));
  }

  f32x4 oacc[2][8] = {};
  for (int ch = 0; ch < 8; ++ch) {
#pragma unroll
    for (int u = 0; u < 4; ++u) {
      int flat = u * 2048 + tid * 8;
      *(bf16x8*)(&wsA[(flat >> 7) * 136 + (flat & 127)]) = pfA[u];
      *(bf16x8*)(&wsB[(flat >> 6) * 72 + (flat & 63)]) = pfB[u];
    }
    __syncthreads();
    if (ch < 7) {
#pragma unroll
      for (int u = 0; u < 4; ++u)
        pfA[u] = *(const bf16x8*)(fc1T + (ch + 1) * 8192 + u * 2048 + tid * 8);
#pragma unroll
      for (int u = 0; u < 4; ++u) {
        int flat = u * 2048 + tid * 8;
        pfB[u] = *(const bf16x8*)(fc2T + (size_t)(flat >> 6) * 512 + (ch + 1) * 64 + (flat & 63));
      }
    }
    // fc1: h[32 x 64] per wave
    f32x4 hacc[2][4] = {};
#pragma unroll
    for (int ks = 0; ks < 4; ++ks)
#pragma unroll
      for (int nt = 0; nt < 4; ++nt) {
        bf16x8 bfr = *(const bf16x8*)(&wsA[(nt * 16 + l15) * 136 + ks * 32 + lhi * 8]);
#pragma unroll
        for (int mt = 0; mt < 2; ++mt)
          hacc[mt][nt] = MFMA(afr[mt][ks], bfr, hacc[mt][nt]);
      }
#pragma unroll
    for (int mt = 0; mt < 2; ++mt)
#pragma unroll
      for (int nt = 0; nt < 4; ++nt)
#pragma unroll
        for (int j = 0; j < 4; ++j) {
          int r = mt * 16 + lhi * 4 + j;
          int hcol = ch * 64 + nt * 16 + l15;
          float hv = hacc[mt][nt][j] + fc1_b[hcol];
          // tanh-GELU: x * sigmoid(1.5957691x + 0.07135482x^3)
          float targ = hv * (1.5957691216f + 0.0713548162f * hv * hv);
          float gv = hv / (1.0f + __expf(-targ));
          hw[r * 72 + nt * 16 + l15] = f2bf(gv);
        }
    WAVE_LDS_FENCE();
    // fc2: accumulate
#pragma unroll
    for (int ks = 0; ks < 2; ++ks) {
      bf16x8 a2[2];
#pragma unroll
      for (int mt = 0; mt < 2; ++mt)
        a2[mt] = *(const bf16x8*)(&hw[(mt * 16 + l15) * 72 + ks * 32 + lhi * 8]);
#pragma unroll
      for (int nt = 0; nt < 8; ++nt) {
        bf16x8 bfr = *(const bf16x8*)(&wsB[(nt * 16 + l15) * 72 + ks * 32 + lhi * 8]);
#pragma unroll
        for (int mt = 0; mt < 2; ++mt)
          oacc[mt][nt] = MFMA(a2[mt], bfr, oacc[mt][nt]);
      }
    }
    WAVE_LDS_FENCE();
    __syncthreads();
  }
#pragma unroll
  for (int mt = 0; mt < 2; ++mt)
#pragma unroll
    for (int nt = 0; nt < 8; ++nt)
#pragma unroll
      for (int j = 0; j < 4; ++j) {
        int r = mbase + mt * 16 + lhi * 4 + j;
        out[(size_t)r * 128 + nt * 16 + l15] = oacc[mt][nt][j] + fc2_b[nt * 16 + l15];
      }
}

// ---------------------------------------------------------------------------
extern "C" void kernel_launch(void* const* d_in, const int* in_sizes, int n_in,
                              void* d_out, int out_size, void* d_ws, size_t ws_size,
                              hipStream_t stream) {
  const float* x      = (const float*)d_in[0];
  const float* mask   = (const float*)d_in[1];
  const int*   rel    = (const int*)d_in[2];
  const float* n1g    = (const float*)d_in[3];
  const float* n1b    = (const float*)d_in[4];
  const float* qkv_w  = (const float*)d_in[5];
  const float* qkv_b  = (const float*)d_in[6];
  const float* rpb    = (const float*)d_in[7];
  const float* proj_w = (const float*)d_in[8];
  const float* proj_b = (const float*)d_in[9];
  const float* n2g    = (const float*)d_in[10];
  const float* n2b    = (const float*)d_in[11];
  const float* fc1_w  = (const float*)d_in[12];
  const float* fc1_b  = (const float*)d_in[13];
  const float* fc2_w  = (const float*)d_in[14];
  const float* fc2_b  = (const float*)d_in[15];
  float* out = (float*)d_out;

  char* ws = (char*)d_ws;
  const size_t SZ = (size_t)NTOK * 128 * 2;
  unsigned short* win   = (unsigned short*)(ws);
  unsigned short* qb    = (unsigned short*)(ws + SZ);
  unsigned short* kb    = (unsigned short*)(ws + 2 * SZ);
  unsigned short* vb    = (unsigned short*)(ws + 3 * SZ);
  unsigned short* qkvT  = (unsigned short*)(ws + 4 * SZ);
  unsigned short* projT = qkvT + 384 * 128;
  unsigned short* fc1T  = projT + 128 * 128;
  unsigned short* fc2T  = fc1T + 512 * 128;
  unsigned short* cmb   = fc2T + 128 * 512;     // 4*256*9604 bf16 = 19.7 MB
  unsigned short* ao = win;
  unsigned short* zb = qb;

  k0_prep<<<256, 256, 0, stream>>>(qkv_w, proj_w, fc1_w, fc2_w, qkvT, projT, fc1T, fc2T);
  k0b_cmb<<<(4 * 256 * NN + 255) / 256, 256, 0, stream>>>(rel, rpb, mask, cmb);
  k1_ln_part<<<NTOK / 4, 256, 0, stream>>>(x, n1g, n1b, win);
  k2_qkv<<<NTOK / 128, 256, 0, stream>>>(win, qkvT, qkv_b, qb, kb, vb);
  k3_attn<<<NWIN * 4, 256, 0, stream>>>(qb, kb, vb, cmb, ao);
  k4_proj_ln<<<NTOK / 128, 256, 0, stream>>>(ao, projT, proj_b, x, n2g, n2b, zb);
  k5_mlp<<<NTOK / 128, 256, 0, stream>>>(zb, fc1T, fc1_b, fc2T, fc2_b, out);
}